// Round 6
// baseline (669.597 us; speedup 1.0000x reference)
//
#include <hip/hip_runtime.h>
#include <math.h>

#define NSLOPE 0.2f

__device__ __forceinline__ float lrelu(float x){ return x > 0.f ? x : NSLOPE * x; }
__device__ __forceinline__ float eluf(float x){ return x > 0.f ? x : expm1f(x); }

__device__ __forceinline__ unsigned short f2bf(float f) {
  unsigned u = __float_as_uint(f);
  u = (u + 0x7fff + ((u >> 16) & 1)) >> 16;   // RNE
  return (unsigned short)u;
}
__device__ __forceinline__ unsigned pk2bf(float a, float b) {
  return (unsigned)f2bf(a) | ((unsigned)f2bf(b) << 16);
}

typedef __attribute__((ext_vector_type(8))) short bf16x8;
typedef __attribute__((ext_vector_type(4))) float f32x4;

// W1[k][n] fp32 -> w1t[n][k] bf16 (256x256)
__global__ __launch_bounds__(256) void conv_w_kernel(const float* __restrict__ W,
                                                     unsigned short* __restrict__ wt) {
  int n = blockIdx.x;      // 0..255
  int k = threadIdx.x;     // 0..255
  wt[n * 256 + k] = f2bf(W[k * 256 + n]);
}

// ---------------- GEMM1 (MFMA): h1b[N,256] = bf16(x[N,256]) @ W1 ----------------
__global__ __launch_bounds__(256) void gemm1_mfma_kernel(const float* __restrict__ x,
                                                         const unsigned short* __restrict__ wt,
                                                         unsigned short* __restrict__ h1b,
                                                         int N) {
  __shared__ __align__(16) unsigned short Asl[128][40];  // [m][k], pitch 80B
  __shared__ __align__(16) unsigned short Bsl[128][40];  // [n][k]
  int tid = threadIdx.x;
  int bm = blockIdx.x >> 1, bn = blockIdx.x & 1;
  int row0 = bm * 128, col0 = bn * 128;

  int lr = tid >> 2;             // 0..63
  int lk = (tid & 3) * 8;        // element offset (8 elems)

  int lane = tid & 63, wv = tid >> 6;
  int m0 = (wv & 1) * 64, n0 = (wv >> 1) * 64;
  int lm = lane & 15, quad = lane >> 4;

  f32x4 acc[4][4];
#pragma unroll
  for (int i = 0; i < 4; ++i)
#pragma unroll
    for (int j = 0; j < 4; ++j) acc[i][j] = (f32x4){0.f, 0.f, 0.f, 0.f};

  for (int kc = 0; kc < 256; kc += 32) {
    float4 a0 = {0,0,0,0}, a1 = {0,0,0,0}, a2 = {0,0,0,0}, a3 = {0,0,0,0};
    int r0 = row0 + lr, r1 = row0 + 64 + lr;
    if (r0 < N) {
      const float4* s0 = (const float4*)(x + (size_t)r0 * 256 + kc + lk);
      a0 = s0[0]; a1 = s0[1];
    }
    if (r1 < N) {
      const float4* s1 = (const float4*)(x + (size_t)r1 * 256 + kc + lk);
      a2 = s1[0]; a3 = s1[1];
    }
    uint4 bv0 = *(const uint4*)(wt + (size_t)(col0 + lr) * 256 + kc + lk);
    uint4 bv1 = *(const uint4*)(wt + (size_t)(col0 + 64 + lr) * 256 + kc + lk);
    uint4 pa0, pa1;
    pa0.x = pk2bf(a0.x, a0.y); pa0.y = pk2bf(a0.z, a0.w);
    pa0.z = pk2bf(a1.x, a1.y); pa0.w = pk2bf(a1.z, a1.w);
    pa1.x = pk2bf(a2.x, a2.y); pa1.y = pk2bf(a2.z, a2.w);
    pa1.z = pk2bf(a3.x, a3.y); pa1.w = pk2bf(a3.z, a3.w);
    __syncthreads();
    *(uint4*)&Asl[lr][lk]      = pa0;
    *(uint4*)&Asl[64 + lr][lk] = pa1;
    *(uint4*)&Bsl[lr][lk]      = bv0;
    *(uint4*)&Bsl[64 + lr][lk] = bv1;
    __syncthreads();
    bf16x8 aF[4], bF[4];
#pragma unroll
    for (int i = 0; i < 4; ++i) aF[i] = *(const bf16x8*)&Asl[m0 + i * 16 + lm][quad * 8];
#pragma unroll
    for (int j = 0; j < 4; ++j) bF[j] = *(const bf16x8*)&Bsl[n0 + j * 16 + lm][quad * 8];
#pragma unroll
    for (int i = 0; i < 4; ++i)
#pragma unroll
      for (int j = 0; j < 4; ++j)
        acc[i][j] = __builtin_amdgcn_mfma_f32_16x16x32_bf16(aF[i], bF[j], acc[i][j], 0, 0, 0);
  }

#pragma unroll
  for (int i = 0; i < 4; ++i) {
#pragma unroll
    for (int j = 0; j < 4; ++j) {
      int gc = col0 + n0 + j * 16 + lm;
      int grb = row0 + m0 + i * 16 + quad * 4;
#pragma unroll
      for (int r = 0; r < 4; ++r) {
        int grow = grb + r;
        if (grow < N) h1b[(size_t)grow * 256 + gc] = f2bf(acc[i][j][r]);
      }
    }
  }
}

// ---------------- att1: a_src/a_dst [N,8] from bf16 h1 ----------------
__global__ __launch_bounds__(256) void att1_kernel(const unsigned short* __restrict__ h1b,
                                                   const float* __restrict__ att_src,
                                                   const float* __restrict__ att_dst,
                                                   float* __restrict__ a_src,
                                                   float* __restrict__ a_dst, int N) {
  __shared__ float sas[256];
  __shared__ float sad[256];
  int tid = threadIdx.x;
  sas[tid] = att_src[tid];
  sad[tid] = att_dst[tid];
  __syncthreads();
  int gid = blockIdx.x * 256 + tid;
  if (gid >= N * 8) return;
  int h = gid & 7;
  const uint4* hv = (const uint4*)(h1b + (size_t)(gid >> 3) * 256 + h * 32);
  float s1 = 0.f, s2 = 0.f;
#pragma unroll
  for (int q = 0; q < 4; ++q) {
    uint4 u = hv[q];
    unsigned uu[4] = {u.x, u.y, u.z, u.w};
#pragma unroll
    for (int e = 0; e < 4; ++e) {
      float lo = __uint_as_float(uu[e] << 16);
      float hi = __uint_as_float(uu[e] & 0xffff0000u);
      int c = h * 32 + q * 8 + e * 2;
      s1 += lo * sas[c] + hi * sas[c + 1];
      s2 += lo * sad[c] + hi * sad[c + 1];
    }
  }
  a_src[gid] = s1;
  a_dst[gid] = s2;
}

// ---------------- CSR build ----------------
__global__ void count_kernel(const int* __restrict__ ei, int* __restrict__ cnt, int E, int N) {
  int e = blockIdx.x * 256 + threadIdx.x;
  if (e >= E + N) return;
  int d = (e < E) ? ei[E + e] : (e - E);
  atomicAdd(&cnt[d], 1);
}

// single-block exclusive scan of cnt[N] -> row_ptr/cursor (1024 threads, ~98 items each)
__global__ __launch_bounds__(1024) void scan_kernel(const int* __restrict__ cnt,
                                                    int* __restrict__ row_ptr,
                                                    int* __restrict__ cursor,
                                                    int N, int Etot) {
  __shared__ int sh[1024];
  int t = threadIdx.x;
  int per = (N + 1023) / 1024;
  int lo = t * per, hi = lo + per;
  if (hi > N) hi = N;
  int s = 0;
  for (int i = lo; i < hi; ++i) s += cnt[i];
  sh[t] = s;
  __syncthreads();
  for (int off = 1; off < 1024; off <<= 1) {
    int v = (t >= off) ? sh[t - off] : 0;
    __syncthreads();
    sh[t] += v;
    __syncthreads();
  }
  int run = sh[t] - s;   // exclusive
  for (int i = lo; i < hi; ++i) {
    int c = cnt[i];
    row_ptr[i] = run;
    cursor[i] = run;
    run += c;
  }
  if (t == 1023) row_ptr[N] = Etot;
}

__global__ void fill_kernel(const int* __restrict__ ei, int* __restrict__ cursor,
                            int* __restrict__ col, int E, int N) {
  int e = blockIdx.x * 256 + threadIdx.x;
  if (e >= E + N) return;
  int s, d;
  if (e < E) { s = ei[e]; d = ei[E + e]; } else { s = e - E; d = s; }
  int pos = atomicAdd(&cursor[d], 1);
  col[pos] = s;
}

// ---------------- agg1: wave per node, single-pass softmax, half-wave gather ----------------
__global__ __launch_bounds__(256) void agg1_kernel(const unsigned short* __restrict__ h1b,
                                                   const float* __restrict__ a_src,
                                                   const float* __restrict__ a_dst,
                                                   const int* __restrict__ row_ptr,
                                                   const int* __restrict__ col,
                                                   const float* __restrict__ b1,
                                                   unsigned short* __restrict__ hmidb, int N) {
  int lane = threadIdx.x & 63;
  int n = blockIdx.x * 4 + (threadIdx.x >> 6);
  if (n >= N) return;
  int beg = row_ptr[n], deg = row_ptr[n + 1] - beg;

  int hA = lane & 7, eoA = lane >> 3;
  float adst = a_dst[n * 8 + hA];

  int half = lane >> 5;     // 0: even edges, 1: odd edges
  int cl = lane & 31;       // channel group: channels cl*8 .. cl*8+7
  int hB = cl >> 2;         // head for this channel group
  float4 acc0 = {0.f,0.f,0.f,0.f}, acc1 = {0.f,0.f,0.f,0.f};
  float den = 0.f;

  for (int c0 = 0; c0 < deg; c0 += 8) {
    int eb = c0 + eoA;
    int ec = eb < deg ? eb : deg - 1;
    int sB = col[beg + ec];
    float exB = 0.f;
    if (eb < deg) exB = __expf(lrelu(a_src[sB * 8 + hA] + adst));
    den += exB;                         // unnormalized denominator
    int rem = deg - c0; if (rem > 8) rem = 8;
#pragma unroll
    for (int p = 0; p < 4; ++p) {
      int myE = 2 * p + half;
      int s = __shfl(sB, myE * 8);
      float al = __shfl(exB, myE * 8 + hB);
      if (myE < rem) {
        uint4 hv = *(const uint4*)(h1b + (size_t)s * 256 + cl * 8);
        acc0.x = fmaf(al, __uint_as_float(hv.x << 16), acc0.x);
        acc0.y = fmaf(al, __uint_as_float(hv.x & 0xffff0000u), acc0.y);
        acc0.z = fmaf(al, __uint_as_float(hv.y << 16), acc0.z);
        acc0.w = fmaf(al, __uint_as_float(hv.y & 0xffff0000u), acc0.w);
        acc1.x = fmaf(al, __uint_as_float(hv.z << 16), acc1.x);
        acc1.y = fmaf(al, __uint_as_float(hv.z & 0xffff0000u), acc1.y);
        acc1.z = fmaf(al, __uint_as_float(hv.w << 16), acc1.z);
        acc1.w = fmaf(al, __uint_as_float(hv.w & 0xffff0000u), acc1.w);
      }
    }
  }
  // reduce den over the 8 edge-offset slots (lane bits 3..5)
#pragma unroll
  for (int off = 8; off < 64; off <<= 1) den += __shfl_xor(den, off);
  float invden = 1.f / (den + 1e-16f);
  float invB = __shfl(invden, hB);     // lane hB has hA==hB

  float po[8] = {acc0.x, acc0.y, acc0.z, acc0.w, acc1.x, acc1.y, acc1.z, acc1.w};
#pragma unroll
  for (int j = 0; j < 8; ++j) po[j] += __shfl(po[j], cl + 32);
  if (half == 0) {
    const float4* b4 = (const float4*)(b1 + cl * 8);
    float4 bb0 = b4[0], bb1 = b4[1];
    float r0 = eluf(fmaf(po[0], invB, bb0.x)), r1 = eluf(fmaf(po[1], invB, bb0.y));
    float r2 = eluf(fmaf(po[2], invB, bb0.z)), r3 = eluf(fmaf(po[3], invB, bb0.w));
    float r4 = eluf(fmaf(po[4], invB, bb1.x)), r5 = eluf(fmaf(po[5], invB, bb1.y));
    float r6 = eluf(fmaf(po[6], invB, bb1.z)), r7 = eluf(fmaf(po[7], invB, bb1.w));
    uint4 ov;
    ov.x = pk2bf(r0, r1); ov.y = pk2bf(r2, r3);
    ov.z = pk2bf(r4, r5); ov.w = pk2bf(r6, r7);
    *(uint4*)(hmidb + (size_t)n * 256 + cl * 8) = ov;
  }
}

// ---------------- GEMM2 (MFMA) + att2: h2b[N,40](bf16) = hmid @ W2; dots fused ----------------
__global__ __launch_bounds__(256) void gemm2_mfma_kernel(const unsigned short* __restrict__ hmidb,
                                                         const float* __restrict__ W2,
                                                         const float* __restrict__ as2,
                                                         const float* __restrict__ ad2,
                                                         unsigned short* __restrict__ h2b,
                                                         float* __restrict__ a_src2,
                                                         float* __restrict__ a_dst2, int N) {
  __shared__ __align__(16) unsigned short Asl[128][40];   // [m][k-slice 32]
  __shared__ __align__(16) unsigned short Bs[48][264];    // W2^T bf16, [n][k]
  __shared__ float asv[48], adv[48];
  int tid = threadIdx.x;
  for (int i = tid; i < 48 * 264 / 2; i += 256) ((unsigned*)Bs)[i] = 0;
  if (tid < 48) {
    asv[tid] = (tid < 40) ? as2[tid] : 0.f;
    adv[tid] = (tid < 40) ? ad2[tid] : 0.f;
  }
  __syncthreads();
  for (int i = tid; i < 256 * 40; i += 256) {
    int k = i / 40, c = i - k * 40;
    Bs[c][k] = f2bf(W2[i]);
  }

  int row0 = blockIdx.x * 128;
  int lane = tid & 63, wv = tid >> 6;
  int lm = lane & 15, quad = lane >> 4;
  int lr = tid >> 1;               // 0..127
  int lk = (tid & 1) * 16;         // 16 bf16 = 32B

  f32x4 acc[2][3];
#pragma unroll
  for (int i = 0; i < 2; ++i)
#pragma unroll
    for (int j = 0; j < 3; ++j) acc[i][j] = (f32x4){0.f,0.f,0.f,0.f};

  for (int kc = 0; kc < 256; kc += 32) {
    uint4 v0 = {0,0,0,0}, v1 = {0,0,0,0};
    int r = row0 + lr;
    if (r < N) {
      const uint4* src = (const uint4*)(hmidb + (size_t)r * 256 + kc + lk);
      v0 = src[0]; v1 = src[1];
    }
    __syncthreads();
    *(uint4*)&Asl[lr][lk]     = v0;
    *(uint4*)&Asl[lr][lk + 8] = v1;
    __syncthreads();
    bf16x8 aF[2], bF[3];
#pragma unroll
    for (int i = 0; i < 2; ++i) aF[i] = *(const bf16x8*)&Asl[wv * 32 + i * 16 + lm][quad * 8];
#pragma unroll
    for (int j = 0; j < 3; ++j) bF[j] = *(const bf16x8*)&Bs[j * 16 + lm][kc + quad * 8];
#pragma unroll
    for (int i = 0; i < 2; ++i)
#pragma unroll
      for (int j = 0; j < 3; ++j)
        acc[i][j] = __builtin_amdgcn_mfma_f32_16x16x32_bf16(aF[i], bF[j], acc[i][j], 0, 0, 0);
  }

#pragma unroll
  for (int i = 0; i < 2; ++i) {
#pragma unroll
    for (int r = 0; r < 4; ++r) {
      int grow = row0 + wv * 32 + i * 16 + quad * 4 + r;
      float vs = 0.f, vd = 0.f;
#pragma unroll
      for (int j = 0; j < 3; ++j) {
        vs = fmaf(acc[i][j][r], asv[j * 16 + lm], vs);
        vd = fmaf(acc[i][j][r], adv[j * 16 + lm], vd);
      }
#pragma unroll
      for (int off = 1; off < 16; off <<= 1) {
        vs += __shfl_xor(vs, off);
        vd += __shfl_xor(vd, off);
      }
      if (grow < N) {
#pragma unroll
        for (int j = 0; j < 3; ++j) {
          int c = j * 16 + lm;
          if (c < 40) h2b[(size_t)grow * 40 + c] = f2bf(acc[i][j][r]);
        }
        if (lm == 0) { a_src2[grow] = vs; a_dst2[grow] = vd; }
      }
    }
  }
}

// ---------------- agg2: wave per node, single-pass softmax, batched exp ----------------
__global__ __launch_bounds__(256) void agg2_kernel(const unsigned short* __restrict__ h2b,
                                                   const float* __restrict__ a_src,
                                                   const float* __restrict__ a_dst,
                                                   const int* __restrict__ row_ptr,
                                                   const int* __restrict__ col,
                                                   const float* __restrict__ b2,
                                                   float* __restrict__ out, int N) {
  int lane = threadIdx.x & 63;
  int n = blockIdx.x * 4 + (threadIdx.x >> 6);
  if (n >= N) return;
  int beg = row_ptr[n], deg = row_ptr[n + 1] - beg;
  float adst = a_dst[n];

  int eg = lane / 10;        // 0..5 edge group (lanes 60-63 idle)
  int cg = lane % 10;        // channels cg*4 .. cg*4+3
  bool active = lane < 60;
  float4 acc = {0.f,0.f,0.f,0.f};
  float den = 0.f;

  for (int c0 = 0; c0 < deg; c0 += 60) {
    int eb = c0 + lane;
    int ec = eb < deg ? eb : deg - 1;
    int sB = col[beg + ec];
    float ex = 0.f;
    if (lane < 60 && eb < deg) ex = __expf(lrelu(a_src[sB] + adst));
    den += ex;
    int rem = deg - c0; if (rem > 60) rem = 60;
    int nst = (rem + 5) / 6;
    for (int st = 0; st < nst; ++st) {
      int lsrc = st * 6 + eg;
      float al = __shfl(ex, lsrc);
      int s = __shfl(sB, lsrc);
      if (active && (c0 + lsrc) < deg) {
        uint2 hv = *(const uint2*)(h2b + (size_t)s * 40 + cg * 4);
        acc.x = fmaf(al, __uint_as_float(hv.x << 16), acc.x);
        acc.y = fmaf(al, __uint_as_float(hv.x & 0xffff0000u), acc.y);
        acc.z = fmaf(al, __uint_as_float(hv.y << 16), acc.z);
        acc.w = fmaf(al, __uint_as_float(hv.y & 0xffff0000u), acc.w);
      }
    }
  }
#pragma unroll
  for (int off = 1; off < 64; off <<= 1) den += __shfl_xor(den, off);
  float inv = 1.f / (den + 1e-16f);

  float4 o = acc;
#pragma unroll
  for (int k = 1; k < 6; ++k) {
    int src = lane + 10 * k;
    o.x += __shfl(acc.x, src);
    o.y += __shfl(acc.y, src);
    o.z += __shfl(acc.z, src);
    o.w += __shfl(acc.w, src);
  }
  if (lane < 10) {
    float4 bb = *(const float4*)(b2 + cg * 4);
    o.x = fmaf(o.x, inv, bb.x);
    o.y = fmaf(o.y, inv, bb.y);
    o.z = fmaf(o.z, inv, bb.z);
    o.w = fmaf(o.w, inv, bb.w);
    *(float4*)(out + (size_t)n * 40 + cg * 4) = o;
  }
}

extern "C" void kernel_launch(void* const* d_in, const int* in_sizes, int n_in,
                              void* d_out, int out_size, void* d_ws, size_t ws_size,
                              hipStream_t stream) {
  const float* x   = (const float*)d_in[0];
  const int*   ei  = (const int*)d_in[1];
  const float* W1  = (const float*)d_in[2];
  const float* as1 = (const float*)d_in[3];
  const float* ad1 = (const float*)d_in[4];
  const float* b1  = (const float*)d_in[5];
  const float* W2  = (const float*)d_in[6];
  const float* as2 = (const float*)d_in[7];
  const float* ad2 = (const float*)d_in[8];
  const float* b2  = (const float*)d_in[9];
  float* out = (float*)d_out;

  int N = in_sizes[0] / 256;
  int E = in_sizes[1] / 2;
  int Etot = E + N;

  char* p = (char*)d_ws;
  auto alloc = [&](size_t bytes) -> char* {
    char* r = p;
    p += (bytes + 255) & ~(size_t)255;
    return r;
  };
  unsigned short* w1t   = (unsigned short*)alloc((size_t)256 * 256 * 2);
  unsigned short* h1b   = (unsigned short*)alloc((size_t)N * 256 * 2);
  unsigned short* hmidb = (unsigned short*)alloc((size_t)N * 256 * 2);
  unsigned short* h2b   = (unsigned short*)alloc((size_t)N * 40 * 2);
  float* a_src1 = (float*)alloc((size_t)N * 8 * 4);
  float* a_dst1 = (float*)alloc((size_t)N * 8 * 4);
  float* a_src2 = (float*)alloc((size_t)N * 4);
  float* a_dst2 = (float*)alloc((size_t)N * 4);
  int* cnt      = (int*)alloc((size_t)N * 4);
  int* cursor   = (int*)alloc((size_t)N * 4);
  int* row_ptr  = (int*)alloc(((size_t)N + 1) * 4);
  int* colx     = (int*)alloc((size_t)Etot * 4);

  hipMemsetAsync(cnt, 0, (size_t)N * 4, stream);

  int nbE = (Etot + 255) / 256;
  count_kernel<<<nbE, 256, 0, stream>>>(ei, cnt, E, N);
  scan_kernel<<<1, 1024, 0, stream>>>(cnt, row_ptr, cursor, N, Etot);
  fill_kernel<<<nbE, 256, 0, stream>>>(ei, cursor, colx, E, N);

  conv_w_kernel<<<256, 256, 0, stream>>>(W1, w1t);
  gemm1_mfma_kernel<<<((N + 127) / 128) * 2, 256, 0, stream>>>(x, w1t, h1b, N);
  att1_kernel<<<(N * 8 + 255) / 256, 256, 0, stream>>>(h1b, as1, ad1, a_src1, a_dst1, N);
  agg1_kernel<<<(N + 3) / 4, 256, 0, stream>>>(h1b, a_src1, a_dst1, row_ptr, colx, b1, hmidb, N);
  gemm2_mfma_kernel<<<(N + 127) / 128, 256, 0, stream>>>(hmidb, W2, as2, ad2, h2b, a_src2, a_dst2, N);
  agg2_kernel<<<(N + 3) / 4, 256, 0, stream>>>(h2b, a_src2, a_dst2, row_ptr, colx, b2, out, N);
}

// Round 7
// 450.786 us; speedup vs baseline: 1.4854x; 1.4854x over previous
//
#include <hip/hip_runtime.h>
#include <math.h>

#define NSLOPE 0.2f

__device__ __forceinline__ float lrelu(float x){ return x > 0.f ? x : NSLOPE * x; }
__device__ __forceinline__ float eluf(float x){ return x > 0.f ? x : expm1f(x); }

__device__ __forceinline__ unsigned short f2bf(float f) {
  unsigned u = __float_as_uint(f);
  u = (u + 0x7fff + ((u >> 16) & 1)) >> 16;   // RNE
  return (unsigned short)u;
}
__device__ __forceinline__ unsigned pk2bf(float a, float b) {
  return (unsigned)f2bf(a) | ((unsigned)f2bf(b) << 16);
}

typedef __attribute__((ext_vector_type(8))) short bf16x8;
typedef __attribute__((ext_vector_type(4))) float f32x4;

// W1[k][n] fp32 -> w1t[n][k] bf16 (256x256)
__global__ __launch_bounds__(256) void conv_w_kernel(const float* __restrict__ W,
                                                     unsigned short* __restrict__ wt) {
  int n = blockIdx.x;      // 0..255
  int k = threadIdx.x;     // 0..255
  wt[n * 256 + k] = f2bf(W[k * 256 + n]);
}

// ---------------- GEMM1 (MFMA): h1b[N,256] = bf16(x[N,256]) @ W1 ----------------
__global__ __launch_bounds__(256) void gemm1_mfma_kernel(const float* __restrict__ x,
                                                         const unsigned short* __restrict__ wt,
                                                         unsigned short* __restrict__ h1b,
                                                         int N) {
  __shared__ __align__(16) unsigned short Asl[128][40];  // [m][k], pitch 80B
  __shared__ __align__(16) unsigned short Bsl[128][40];  // [n][k]
  int tid = threadIdx.x;
  int bm = blockIdx.x >> 1, bn = blockIdx.x & 1;
  int row0 = bm * 128, col0 = bn * 128;

  int lr = tid >> 2;             // 0..63
  int lk = (tid & 3) * 8;        // element offset (8 elems)

  int lane = tid & 63, wv = tid >> 6;
  int m0 = (wv & 1) * 64, n0 = (wv >> 1) * 64;
  int lm = lane & 15, quad = lane >> 4;

  f32x4 acc[4][4];
#pragma unroll
  for (int i = 0; i < 4; ++i)
#pragma unroll
    for (int j = 0; j < 4; ++j) acc[i][j] = (f32x4){0.f, 0.f, 0.f, 0.f};

  for (int kc = 0; kc < 256; kc += 32) {
    float4 a0 = {0,0,0,0}, a1 = {0,0,0,0}, a2 = {0,0,0,0}, a3 = {0,0,0,0};
    int r0 = row0 + lr, r1 = row0 + 64 + lr;
    if (r0 < N) {
      const float4* s0 = (const float4*)(x + (size_t)r0 * 256 + kc + lk);
      a0 = s0[0]; a1 = s0[1];
    }
    if (r1 < N) {
      const float4* s1 = (const float4*)(x + (size_t)r1 * 256 + kc + lk);
      a2 = s1[0]; a3 = s1[1];
    }
    uint4 bv0 = *(const uint4*)(wt + (size_t)(col0 + lr) * 256 + kc + lk);
    uint4 bv1 = *(const uint4*)(wt + (size_t)(col0 + 64 + lr) * 256 + kc + lk);
    uint4 pa0, pa1;
    pa0.x = pk2bf(a0.x, a0.y); pa0.y = pk2bf(a0.z, a0.w);
    pa0.z = pk2bf(a1.x, a1.y); pa0.w = pk2bf(a1.z, a1.w);
    pa1.x = pk2bf(a2.x, a2.y); pa1.y = pk2bf(a2.z, a2.w);
    pa1.z = pk2bf(a3.x, a3.y); pa1.w = pk2bf(a3.z, a3.w);
    __syncthreads();
    *(uint4*)&Asl[lr][lk]      = pa0;
    *(uint4*)&Asl[64 + lr][lk] = pa1;
    *(uint4*)&Bsl[lr][lk]      = bv0;
    *(uint4*)&Bsl[64 + lr][lk] = bv1;
    __syncthreads();
    bf16x8 aF[4], bF[4];
#pragma unroll
    for (int i = 0; i < 4; ++i) aF[i] = *(const bf16x8*)&Asl[m0 + i * 16 + lm][quad * 8];
#pragma unroll
    for (int j = 0; j < 4; ++j) bF[j] = *(const bf16x8*)&Bsl[n0 + j * 16 + lm][quad * 8];
#pragma unroll
    for (int i = 0; i < 4; ++i)
#pragma unroll
      for (int j = 0; j < 4; ++j)
        acc[i][j] = __builtin_amdgcn_mfma_f32_16x16x32_bf16(aF[i], bF[j], acc[i][j], 0, 0, 0);
  }

#pragma unroll
  for (int i = 0; i < 4; ++i) {
#pragma unroll
    for (int j = 0; j < 4; ++j) {
      int gc = col0 + n0 + j * 16 + lm;
      int grb = row0 + m0 + i * 16 + quad * 4;
#pragma unroll
      for (int r = 0; r < 4; ++r) {
        int grow = grb + r;
        if (grow < N) h1b[(size_t)grow * 256 + gc] = f2bf(acc[i][j][r]);
      }
    }
  }
}

// ---------------- att1: a_src/a_dst [N,8] from bf16 h1 ----------------
__global__ __launch_bounds__(256) void att1_kernel(const unsigned short* __restrict__ h1b,
                                                   const float* __restrict__ att_src,
                                                   const float* __restrict__ att_dst,
                                                   float* __restrict__ a_src,
                                                   float* __restrict__ a_dst, int N) {
  __shared__ float sas[256];
  __shared__ float sad[256];
  int tid = threadIdx.x;
  sas[tid] = att_src[tid];
  sad[tid] = att_dst[tid];
  __syncthreads();
  int gid = blockIdx.x * 256 + tid;
  if (gid >= N * 8) return;
  int h = gid & 7;
  const uint4* hv = (const uint4*)(h1b + (size_t)(gid >> 3) * 256 + h * 32);
  float s1 = 0.f, s2 = 0.f;
#pragma unroll
  for (int q = 0; q < 4; ++q) {
    uint4 u = hv[q];
    unsigned uu[4] = {u.x, u.y, u.z, u.w};
#pragma unroll
    for (int e = 0; e < 4; ++e) {
      float lo = __uint_as_float(uu[e] << 16);
      float hi = __uint_as_float(uu[e] & 0xffff0000u);
      int c = h * 32 + q * 8 + e * 2;
      s1 += lo * sas[c] + hi * sas[c + 1];
      s2 += lo * sad[c] + hi * sad[c + 1];
    }
  }
  a_src[gid] = s1;
  a_dst[gid] = s2;
}

// ---------------- CSR build ----------------
__global__ void count_kernel(const int* __restrict__ ei, int* __restrict__ cnt, int E, int N) {
  int e = blockIdx.x * 256 + threadIdx.x;
  if (e >= E + N) return;
  int d = (e < E) ? ei[E + e] : (e - E);
  atomicAdd(&cnt[d], 1);
}

__global__ __launch_bounds__(256) void scan1_kernel(const int* __restrict__ cnt,
                                                    int* __restrict__ tmp,
                                                    int* __restrict__ bsum, int N) {
  __shared__ int sh[256];
  int t = threadIdx.x;
  int base = blockIdx.x * 1024 + t * 4;
  int v[4]; int s = 0;
#pragma unroll
  for (int j = 0; j < 4; ++j) { v[j] = (base + j < N) ? cnt[base + j] : 0; s += v[j]; }
  sh[t] = s;
  __syncthreads();
  for (int off = 1; off < 256; off <<= 1) {
    int xv = (t >= off) ? sh[t - off] : 0;
    __syncthreads();
    sh[t] += xv;
    __syncthreads();
  }
  if (t == 255) bsum[blockIdx.x] = sh[255];
  int run = sh[t] - s;  // exclusive
#pragma unroll
  for (int j = 0; j < 4; ++j) {
    if (base + j < N) tmp[base + j] = run;
    run += v[j];
  }
}

__global__ __launch_bounds__(128) void scan2_kernel(const int* __restrict__ bsum,
                                                    int* __restrict__ boff, int nb) {
  __shared__ int sh[128];
  int t = threadIdx.x;
  int v = (t < nb) ? bsum[t] : 0;
  sh[t] = v;
  __syncthreads();
  for (int off = 1; off < 128; off <<= 1) {
    int xv = (t >= off) ? sh[t - off] : 0;
    __syncthreads();
    sh[t] += xv;
    __syncthreads();
  }
  if (t < nb) boff[t] = sh[t] - v;
}

__global__ void scan3_kernel(const int* __restrict__ tmp, const int* __restrict__ boff,
                             int* __restrict__ row_ptr, int* __restrict__ cursor,
                             int N, int Etot) {
  int i = blockIdx.x * 256 + threadIdx.x;
  if (i == 0) row_ptr[N] = Etot;
  if (i >= N) return;
  int rp = tmp[i] + boff[i >> 10];
  row_ptr[i] = rp;
  cursor[i] = rp;
}

__global__ void fill_kernel(const int* __restrict__ ei, int* __restrict__ cursor,
                            int* __restrict__ col, int E, int N) {
  int e = blockIdx.x * 256 + threadIdx.x;
  if (e >= E + N) return;
  int s, d;
  if (e < E) { s = ei[e]; d = ei[E + e]; } else { s = e - E; d = s; }
  int pos = atomicAdd(&cursor[d], 1);
  col[pos] = s;
}

// ---------------- agg1: wave per node, single-pass softmax, half-wave gather ----------------
__global__ __launch_bounds__(256) void agg1_kernel(const unsigned short* __restrict__ h1b,
                                                   const float* __restrict__ a_src,
                                                   const float* __restrict__ a_dst,
                                                   const int* __restrict__ row_ptr,
                                                   const int* __restrict__ col,
                                                   const float* __restrict__ b1,
                                                   unsigned short* __restrict__ hmidb, int N) {
  int lane = threadIdx.x & 63;
  int n = blockIdx.x * 4 + (threadIdx.x >> 6);
  if (n >= N) return;
  int beg = row_ptr[n], deg = row_ptr[n + 1] - beg;

  int hA = lane & 7, eoA = lane >> 3;
  float adst = a_dst[n * 8 + hA];

  int half = lane >> 5;     // 0: even edges, 1: odd edges
  int cl = lane & 31;       // channel group: channels cl*8 .. cl*8+7
  int hB = cl >> 2;         // head for this channel group
  float4 acc0 = {0.f,0.f,0.f,0.f}, acc1 = {0.f,0.f,0.f,0.f};
  float den = 0.f;

  for (int c0 = 0; c0 < deg; c0 += 8) {
    int eb = c0 + eoA;
    int ec = eb < deg ? eb : deg - 1;
    int sB = col[beg + ec];
    float exB = 0.f;
    if (eb < deg) exB = __expf(lrelu(a_src[sB * 8 + hA] + adst));
    den += exB;                         // unnormalized denominator
    int rem = deg - c0; if (rem > 8) rem = 8;
#pragma unroll
    for (int p = 0; p < 4; ++p) {
      int myE = 2 * p + half;
      int s = __shfl(sB, myE * 8);
      float al = __shfl(exB, myE * 8 + hB);
      if (myE < rem) {
        uint4 hv = *(const uint4*)(h1b + (size_t)s * 256 + cl * 8);
        acc0.x = fmaf(al, __uint_as_float(hv.x << 16), acc0.x);
        acc0.y = fmaf(al, __uint_as_float(hv.x & 0xffff0000u), acc0.y);
        acc0.z = fmaf(al, __uint_as_float(hv.y << 16), acc0.z);
        acc0.w = fmaf(al, __uint_as_float(hv.y & 0xffff0000u), acc0.w);
        acc1.x = fmaf(al, __uint_as_float(hv.z << 16), acc1.x);
        acc1.y = fmaf(al, __uint_as_float(hv.z & 0xffff0000u), acc1.y);
        acc1.z = fmaf(al, __uint_as_float(hv.w << 16), acc1.z);
        acc1.w = fmaf(al, __uint_as_float(hv.w & 0xffff0000u), acc1.w);
      }
    }
  }
  // reduce den over the 8 edge-offset slots (lane bits 3..5)
#pragma unroll
  for (int off = 8; off < 64; off <<= 1) den += __shfl_xor(den, off);
  float invden = 1.f / (den + 1e-16f);
  float invB = __shfl(invden, hB);     // lane hB has hA==hB

  float po[8] = {acc0.x, acc0.y, acc0.z, acc0.w, acc1.x, acc1.y, acc1.z, acc1.w};
#pragma unroll
  for (int j = 0; j < 8; ++j) po[j] += __shfl(po[j], cl + 32);
  if (half == 0) {
    const float4* b4 = (const float4*)(b1 + cl * 8);
    float4 bb0 = b4[0], bb1 = b4[1];
    float r0 = eluf(fmaf(po[0], invB, bb0.x)), r1 = eluf(fmaf(po[1], invB, bb0.y));
    float r2 = eluf(fmaf(po[2], invB, bb0.z)), r3 = eluf(fmaf(po[3], invB, bb0.w));
    float r4 = eluf(fmaf(po[4], invB, bb1.x)), r5 = eluf(fmaf(po[5], invB, bb1.y));
    float r6 = eluf(fmaf(po[6], invB, bb1.z)), r7 = eluf(fmaf(po[7], invB, bb1.w));
    uint4 ov;
    ov.x = pk2bf(r0, r1); ov.y = pk2bf(r2, r3);
    ov.z = pk2bf(r4, r5); ov.w = pk2bf(r6, r7);
    *(uint4*)(hmidb + (size_t)n * 256 + cl * 8) = ov;
  }
}

// ---------------- GEMM2 (MFMA) + att2: h2b[N,40](bf16) = hmid @ W2; dots fused ----------------
__global__ __launch_bounds__(256) void gemm2_mfma_kernel(const unsigned short* __restrict__ hmidb,
                                                         const float* __restrict__ W2,
                                                         const float* __restrict__ as2,
                                                         const float* __restrict__ ad2,
                                                         unsigned short* __restrict__ h2b,
                                                         float* __restrict__ a_src2,
                                                         float* __restrict__ a_dst2, int N) {
  __shared__ __align__(16) unsigned short Asl[128][40];   // [m][k-slice 32]
  __shared__ __align__(16) unsigned short Bs[48][264];    // W2^T bf16, [n][k]
  __shared__ float asv[48], adv[48];
  int tid = threadIdx.x;
  for (int i = tid; i < 48 * 264 / 2; i += 256) ((unsigned*)Bs)[i] = 0;
  if (tid < 48) {
    asv[tid] = (tid < 40) ? as2[tid] : 0.f;
    adv[tid] = (tid < 40) ? ad2[tid] : 0.f;
  }
  __syncthreads();
  for (int i = tid; i < 256 * 40; i += 256) {
    int k = i / 40, c = i - k * 40;
    Bs[c][k] = f2bf(W2[i]);
  }

  int row0 = blockIdx.x * 128;
  int lane = tid & 63, wv = tid >> 6;
  int lm = lane & 15, quad = lane >> 4;
  int lr = tid >> 1;               // 0..127
  int lk = (tid & 1) * 16;         // 16 bf16 = 32B

  f32x4 acc[2][3];
#pragma unroll
  for (int i = 0; i < 2; ++i)
#pragma unroll
    for (int j = 0; j < 3; ++j) acc[i][j] = (f32x4){0.f,0.f,0.f,0.f};

  for (int kc = 0; kc < 256; kc += 32) {
    uint4 v0 = {0,0,0,0}, v1 = {0,0,0,0};
    int r = row0 + lr;
    if (r < N) {
      const uint4* src = (const uint4*)(hmidb + (size_t)r * 256 + kc + lk);
      v0 = src[0]; v1 = src[1];
    }
    __syncthreads();
    *(uint4*)&Asl[lr][lk]     = v0;
    *(uint4*)&Asl[lr][lk + 8] = v1;
    __syncthreads();
    bf16x8 aF[2], bF[3];
#pragma unroll
    for (int i = 0; i < 2; ++i) aF[i] = *(const bf16x8*)&Asl[wv * 32 + i * 16 + lm][quad * 8];
#pragma unroll
    for (int j = 0; j < 3; ++j) bF[j] = *(const bf16x8*)&Bs[j * 16 + lm][kc + quad * 8];
#pragma unroll
    for (int i = 0; i < 2; ++i)
#pragma unroll
      for (int j = 0; j < 3; ++j)
        acc[i][j] = __builtin_amdgcn_mfma_f32_16x16x32_bf16(aF[i], bF[j], acc[i][j], 0, 0, 0);
  }

#pragma unroll
  for (int i = 0; i < 2; ++i) {
#pragma unroll
    for (int r = 0; r < 4; ++r) {
      int grow = row0 + wv * 32 + i * 16 + quad * 4 + r;
      float vs = 0.f, vd = 0.f;
#pragma unroll
      for (int j = 0; j < 3; ++j) {
        vs = fmaf(acc[i][j][r], asv[j * 16 + lm], vs);
        vd = fmaf(acc[i][j][r], adv[j * 16 + lm], vd);
      }
#pragma unroll
      for (int off = 1; off < 16; off <<= 1) {
        vs += __shfl_xor(vs, off);
        vd += __shfl_xor(vd, off);
      }
      if (grow < N) {
#pragma unroll
        for (int j = 0; j < 3; ++j) {
          int c = j * 16 + lm;
          if (c < 40) h2b[(size_t)grow * 40 + c] = f2bf(acc[i][j][r]);
        }
        if (lm == 0) { a_src2[grow] = vs; a_dst2[grow] = vd; }
      }
    }
  }
}

// ---------------- agg2: wave per node, single-pass softmax, batched exp ----------------
__global__ __launch_bounds__(256) void agg2_kernel(const unsigned short* __restrict__ h2b,
                                                   const float* __restrict__ a_src,
                                                   const float* __restrict__ a_dst,
                                                   const int* __restrict__ row_ptr,
                                                   const int* __restrict__ col,
                                                   const float* __restrict__ b2,
                                                   float* __restrict__ out, int N) {
  int lane = threadIdx.x & 63;
  int n = blockIdx.x * 4 + (threadIdx.x >> 6);
  if (n >= N) return;
  int beg = row_ptr[n], deg = row_ptr[n + 1] - beg;
  float adst = a_dst[n];

  int eg = lane / 10;        // 0..5 edge group (lanes 60-63 idle)
  int cg = lane % 10;        // channels cg*4 .. cg*4+3
  bool active = lane < 60;
  float4 acc = {0.f,0.f,0.f,0.f};
  float den = 0.f;

  for (int c0 = 0; c0 < deg; c0 += 60) {
    int eb = c0 + lane;
    int ec = eb < deg ? eb : deg - 1;
    int sB = col[beg + ec];
    float ex = 0.f;
    if (lane < 60 && eb < deg) ex = __expf(lrelu(a_src[sB] + adst));
    den += ex;
    int rem = deg - c0; if (rem > 60) rem = 60;
    int nst = (rem + 5) / 6;
    for (int st = 0; st < nst; ++st) {
      int lsrc = st * 6 + eg;
      float al = __shfl(ex, lsrc);
      int s = __shfl(sB, lsrc);
      if (active && (c0 + lsrc) < deg) {
        uint2 hv = *(const uint2*)(h2b + (size_t)s * 40 + cg * 4);
        acc.x = fmaf(al, __uint_as_float(hv.x << 16), acc.x);
        acc.y = fmaf(al, __uint_as_float(hv.x & 0xffff0000u), acc.y);
        acc.z = fmaf(al, __uint_as_float(hv.y << 16), acc.z);
        acc.w = fmaf(al, __uint_as_float(hv.y & 0xffff0000u), acc.w);
      }
    }
  }
#pragma unroll
  for (int off = 1; off < 64; off <<= 1) den += __shfl_xor(den, off);
  float inv = 1.f / (den + 1e-16f);

  float4 o = acc;
#pragma unroll
  for (int k = 1; k < 6; ++k) {
    int src = lane + 10 * k;
    o.x += __shfl(acc.x, src);
    o.y += __shfl(acc.y, src);
    o.z += __shfl(acc.z, src);
    o.w += __shfl(acc.w, src);
  }
  if (lane < 10) {
    float4 bb = *(const float4*)(b2 + cg * 4);
    o.x = fmaf(o.x, inv, bb.x);
    o.y = fmaf(o.y, inv, bb.y);
    o.z = fmaf(o.z, inv, bb.z);
    o.w = fmaf(o.w, inv, bb.w);
    *(float4*)(out + (size_t)n * 40 + cg * 4) = o;
  }
}

extern "C" void kernel_launch(void* const* d_in, const int* in_sizes, int n_in,
                              void* d_out, int out_size, void* d_ws, size_t ws_size,
                              hipStream_t stream) {
  const float* x   = (const float*)d_in[0];
  const int*   ei  = (const int*)d_in[1];
  const float* W1  = (const float*)d_in[2];
  const float* as1 = (const float*)d_in[3];
  const float* ad1 = (const float*)d_in[4];
  const float* b1  = (const float*)d_in[5];
  const float* W2  = (const float*)d_in[6];
  const float* as2 = (const float*)d_in[7];
  const float* ad2 = (const float*)d_in[8];
  const float* b2  = (const float*)d_in[9];
  float* out = (float*)d_out;

  int N = in_sizes[0] / 256;
  int E = in_sizes[1] / 2;
  int Etot = E + N;

  char* p = (char*)d_ws;
  auto alloc = [&](size_t bytes) -> char* {
    char* r = p;
    p += (bytes + 255) & ~(size_t)255;
    return r;
  };
  unsigned short* w1t   = (unsigned short*)alloc((size_t)256 * 256 * 2);
  unsigned short* h1b   = (unsigned short*)alloc((size_t)N * 256 * 2);
  unsigned short* hmidb = (unsigned short*)alloc((size_t)N * 256 * 2);
  unsigned short* h2b   = (unsigned short*)alloc((size_t)N * 40 * 2);
  float* a_src1 = (float*)alloc((size_t)N * 8 * 4);
  float* a_dst1 = (float*)alloc((size_t)N * 8 * 4);
  float* a_src2 = (float*)alloc((size_t)N * 4);
  float* a_dst2 = (float*)alloc((size_t)N * 4);
  int* cnt      = (int*)alloc((size_t)N * 4);
  int* cursor   = (int*)alloc((size_t)N * 4);
  int* row_ptr  = (int*)alloc(((size_t)N + 1) * 4);
  int* tmp      = (int*)alloc((size_t)N * 4);
  int* bsum     = (int*)alloc(512);
  int* boff     = (int*)alloc(512);
  int* colx     = (int*)alloc((size_t)Etot * 4);

  hipMemsetAsync(cnt, 0, (size_t)N * 4, stream);

  int nbE = (Etot + 255) / 256;
  int nb1 = (N + 1023) / 1024;
  count_kernel<<<nbE, 256, 0, stream>>>(ei, cnt, E, N);
  scan1_kernel<<<nb1, 256, 0, stream>>>(cnt, tmp, bsum, N);
  scan2_kernel<<<1, 128, 0, stream>>>(bsum, boff, nb1);
  scan3_kernel<<<(N + 255) / 256, 256, 0, stream>>>(tmp, boff, row_ptr, cursor, N, Etot);
  fill_kernel<<<nbE, 256, 0, stream>>>(ei, cursor, colx, E, N);

  conv_w_kernel<<<256, 256, 0, stream>>>(W1, w1t);
  gemm1_mfma_kernel<<<((N + 127) / 128) * 2, 256, 0, stream>>>(x, w1t, h1b, N);
  att1_kernel<<<(N * 8 + 255) / 256, 256, 0, stream>>>(h1b, as1, ad1, a_src1, a_dst1, N);
  agg1_kernel<<<(N + 3) / 4, 256, 0, stream>>>(h1b, a_src1, a_dst1, row_ptr, colx, b1, hmidb, N);
  gemm2_mfma_kernel<<<(N + 127) / 128, 256, 0, stream>>>(hmidb, W2, as2, ad2, h2b, a_src2, a_dst2, N);
  agg2_kernel<<<(N + 3) / 4, 256, 0, stream>>>(h2b, a_src2, a_dst2, row_ptr, colx, b2, out, N);
}